// Round 3
// baseline (1177.083 us; speedup 1.0000x reference)
//
#include <hip/hip_runtime.h>
#include <stdint.h>

// Problem constants (fixed by the reference).
#define Bn 2
#define Hn 16
#define Sn 2048
#define Dn 64
#define TQ 16                  // q rows per workgroup
#define KSPLIT 8               // k-range split across workgroups
#define KRANGE (Sn / KSPLIT)   // 256
#define KC 64                  // k columns per phase cycle (chunk)
#define NCHUNK (KRANGE / KC)   // 4
#define EPAD 72                // ebuf row length in shorts: 144 B, 16B-aligned for b128

typedef __attribute__((ext_vector_type(8))) short short8;
typedef __attribute__((ext_vector_type(4))) short short4v;
typedef __attribute__((ext_vector_type(4))) float float4v;

__device__ __forceinline__ short f2bf(float f) {
    uint32_t u = __builtin_bit_cast(uint32_t, f);
    u += 0x7fffu + ((u >> 16) & 1u);   // round-to-nearest-even
    return (short)(u >> 16);
}
__device__ __forceinline__ float bf2f(short s) {
    uint32_t u = ((uint32_t)(uint16_t)s) << 16;
    return __builtin_bit_cast(float, u);
}
// Load 8 consecutive fp32, convert to a bf16x8 MFMA fragment.
__device__ __forceinline__ short8 load_bf8(const float* p) {
    float4v a = *(const float4v*)p;
    float4v b = *(const float4v*)(p + 4);
    short8 r;
    r[0] = f2bf(a[0]); r[1] = f2bf(a[1]); r[2] = f2bf(a[2]); r[3] = f2bf(a[3]);
    r[4] = f2bf(b[0]); r[5] = f2bf(b[1]); r[6] = f2bf(b[2]); r[7] = f2bf(b[3]);
    return r;
}

#define MFMA(a, b, c) __builtin_amdgcn_mfma_f32_16x16x32_bf16((a), (b), (c), 0, 0, 0)
#define EXP2S 0.18033688011112042f   // log2(e) / 8: exp(s/8) == exp2(s * EXP2S)

// Grid: 2048 blocks of 512 threads. Block = 8 waves; wave w owns heads {2w,2w+1}
// for a 16-row q tile and a 256-wide k range (KSPLIT=8), processed in 4 chunks
// of 64 k. Per chunk, three phases separated by 2 barriers:
//   phase1 : QK^T + exp -> bf16 ebuf[h][q][k]   (wave-private head rows)
//   phase2a: rden[q][k] = 1 / sum over 16 heads (threads 0..255, after barrier)
//   phase2b: attn = e*rden -> NT store; PV MFMA (ebuf row IS the PV A-frag)
// LDS sized to EXACTLY 40960 B so 4 blocks/CU fit (160 KiB); launch_bounds
// (512,8) caps VGPRs at 64 (the natural allocation measured in round 2) so the
// wave-slot limit, not registers, binds -> target 32 waves/CU for latency hiding.
__global__ __launch_bounds__(512, 8) void attn_fused(
    const float* __restrict__ Q, const float* __restrict__ K,
    const float* __restrict__ V, float* __restrict__ Out,
    float* __restrict__ Attn)
{
    // LDS: 16*16*72*2 + 16*64*4 = 36864 + 4096 = 40960 B -> 4 blocks/CU
    __shared__ short ebuf[Hn][TQ][EPAD];   // e = exp(score/8), bf16, [head][q][k+pad]
    __shared__ float rden[TQ][KC];         // RECIPROCAL softmax denominators, [q][k]

    // Bijective XCD swizzle (2048 = 8 * 256): each XCD gets a contiguous chunk
    // of qb values sharing (b,ks) -> K/V panel L2 reuse (2 panels = 4 MB per L2).
    const int bid0 = blockIdx.x;
    const int bid  = (bid0 & 7) * 256 + (bid0 >> 3);

    const int qb = bid & 127;
    const int t2 = bid >> 7;
    const int ks = t2 & 7;
    const int b  = t2 >> 3;

    const int tid  = threadIdx.x;
    const int wave = tid >> 6;
    const int lane = tid & 63;
    const int quad = lane >> 4;
    const int l16  = lane & 15;

    const int h0 = wave * 2;
    const int q0 = qb * TQ;
    const int k0 = ks * KRANGE;

    // Resident Q fragments: A[m=l16][kdim=quad*8+j] per (head, d-chunk of 32).
    short8 aq[2][2];
#pragma unroll
    for (int hi = 0; hi < 2; ++hi) {
        const float* qp = Q + ((size_t)(b * Hn + h0 + hi) * Sn + (size_t)(q0 + l16)) * Dn
                            + quad * 8;
        aq[hi][0] = load_bf8(qp);
        aq[hi][1] = load_bf8(qp + 32);
    }

    // Out accumulators: [head][d-chunk] 16x16 C-frags.
    float4v acc[2][4];
#pragma unroll
    for (int hi = 0; hi < 2; ++hi)
#pragma unroll
        for (int dc = 0; dc < 4; ++dc)
            acc[hi][dc] = (float4v){0.f, 0.f, 0.f, 0.f};

    for (int chunk = 0; chunk < NCHUNK; ++chunk) {
        const int kb = k0 + chunk * KC;

        // ---- phase 1: QK^T + exp for own 2 heads, 4 independent k-tiles ----
#pragma unroll
        for (int hi = 0; hi < 2; ++hi) {
            const int h = h0 + hi;
            const float* kbase = K + (size_t)(b * Hn + h) * Sn * Dn;
#pragma unroll
            for (int kt = 0; kt < KC / 16; ++kt) {
                const float* kp = kbase + (size_t)(kb + kt * 16 + l16) * Dn + quad * 8;
                short8 bk0 = load_bf8(kp);
                short8 bk1 = load_bf8(kp + 32);
                float4v c = (float4v){0.f, 0.f, 0.f, 0.f};
                c = MFMA(aq[hi][0], bk0, c);
                c = MFMA(aq[hi][1], bk1, c);
                // C-layout: lane holds (q = quad*4+r, k = kt*16+l16).
#pragma unroll
                for (int r = 0; r < 4; ++r)
                    ebuf[h][quad * 4 + r][kt * 16 + l16] =
                        f2bf(__builtin_amdgcn_exp2f(c[r] * EXP2S));
            }
        }
        __syncthreads();   // [A] publish ebuf

        // ---- phase 2a: rden[q][k] = 1/sum over 16 heads (256 thr x 4 k) ----
        if (tid < 256) {
            const int q  = tid >> 4;          // 0..15
            const int k4 = (tid & 15) * 4;    // 0..60
            float4v s = (float4v){0.f, 0.f, 0.f, 0.f};
#pragma unroll
            for (int h = 0; h < Hn; ++h) {
                short4v v4 = *(const short4v*)&ebuf[h][q][k4];
                s[0] += bf2f(v4[0]); s[1] += bf2f(v4[1]);
                s[2] += bf2f(v4[2]); s[3] += bf2f(v4[3]);
            }
            float4v r;
#pragma unroll
            for (int j = 0; j < 4; ++j) r[j] = __builtin_amdgcn_rcpf(s[j]);
            *(float4v*)&rden[q][k4] = r;
        }
        __syncthreads();   // [B] publish rden

        // ---- phase 2b: attn = e*rden -> NT store; PV (no barriers) ----
#pragma unroll
        for (int c2 = 0; c2 < KC / 32; ++c2) {
            const int kk = c2 * 32 + quad * 8;   // this lane's 8-col window
            float4v dA = *(const float4v*)&rden[l16][kk];
            float4v dB = *(const float4v*)&rden[l16][kk + 4];
#pragma unroll
            for (int hi = 0; hi < 2; ++hi) {
                const int h = h0 + hi;
                // ebuf row = PV A-frag: A[m=l16][kslot=quad*8+j], one b128.
                short8 ef = *(const short8*)&ebuf[h][l16][kk];
                float4v a0, a1;
#pragma unroll
                for (int j = 0; j < 4; ++j) {
                    a0[j] = bf2f(ef[j])     * dA[j];
                    a1[j] = bf2f(ef[4 + j]) * dB[j];
                }
                // attn store: lane writes 32B contiguous (row q0+l16, cols kb+kk..+7)
                float* ap = Attn + ((size_t)(b * Hn + h) * Sn + (size_t)(q0 + l16)) * Sn
                            + kb + kk;
                __builtin_nontemporal_store(a0, (float4v*)ap);
                __builtin_nontemporal_store(a1, (float4v*)ap + 1);
                short8 av;
#pragma unroll
                for (int j = 0; j < 4; ++j) { av[j] = f2bf(a0[j]); av[4 + j] = f2bf(a1[j]); }
                // V B-frag: B[kslot=quad*8+j][n=dc*16+l16], physical k = kb+kk+j.
                const float* vbase = V + ((size_t)(b * Hn + h) * Sn + (size_t)(kb + kk)) * Dn;
#pragma unroll
                for (int dc = 0; dc < 4; ++dc) {
                    short8 bv;
#pragma unroll
                    for (int j = 0; j < 8; ++j)
                        bv[j] = f2bf(vbase[(size_t)j * Dn + dc * 16 + l16]);
                    acc[hi][dc] = MFMA(av, bv, acc[hi][dc]);
                }
            }
        }
        // no barrier at chunk end: next phase1 writes only own-head ebuf rows,
        // and the next rden write sits behind barrier [A] of chunk i+1, which
        // every wave reaches only after finishing its phase2b of chunk i.
    }

    // --- epilogue: atomic-accumulate the k-split partials into Out ---
#pragma unroll
    for (int hi = 0; hi < 2; ++hi)
#pragma unroll
        for (int dc = 0; dc < 4; ++dc) {
            float* op = Out + ((size_t)(b * Hn + h0 + hi) * Sn + (size_t)(q0 + quad * 4)) * Dn
                        + dc * 16 + l16;
#pragma unroll
            for (int r = 0; r < 4; ++r)
                unsafeAtomicAdd(op + (size_t)r * Dn, acc[hi][dc][r]);
        }
}

extern "C" void kernel_launch(void* const* d_in, const int* in_sizes, int n_in,
                              void* d_out, int out_size, void* d_ws, size_t ws_size,
                              hipStream_t stream) {
    const float* q = (const float*)d_in[0];
    const float* k = (const float*)d_in[1];
    const float* v = (const float*)d_in[2];
    float* out  = (float*)d_out;
    float* attn = out + (size_t)Bn * Hn * Sn * Dn;   // outputs concatenated: (out, attn)

    // Out is accumulated via atomics across KSPLIT partials -> zero it first.
    hipMemsetAsync(d_out, 0, (size_t)Bn * Hn * Sn * Dn * sizeof(float), stream);

    attn_fused<<<dim3(Bn * (Sn / TQ) * KSPLIT), dim3(512), 0, stream>>>(q, k, v, out, attn);
}